// Round 1
// baseline (348.085 us; speedup 1.0000x reference)
//
#include <hip/hip_runtime.h>

#define HD 32

__device__ __forceinline__ float tanh_fast(float x) {
    // tanh(x) = 1 - 2/(exp(2x)+1); saturates correctly for |x| large.
    float t = __expf(2.0f * x);
    return 1.0f - __fdividef(2.0f, t + 1.0f);
}

__device__ __forceinline__ float softplus_fast(float x) {
    // pre-activation bounded (|x| <~ 5) given h2 in (-1,1), W3 ~ N(0,1/sqrt(32))
    return __logf(1.0f + __expf(x));
}

__device__ __forceinline__ float mlp_f(float e, float g,
        const float* __restrict__ W1, const float* __restrict__ b1,
        const float* __restrict__ W2, const float* __restrict__ b2,
        const float* __restrict__ W3, float b3v)
{
    // layer 1: x = [e, g] (2 features) -> h1 = tanh(x @ W1 + b1)
    float h1[HD];
#pragma unroll
    for (int j = 0; j < HD; ++j) {
        float pre = fmaf(e, W1[j], fmaf(g, W1[HD + j], b1[j]));
        h1[j] = tanh_fast(pre);
    }
    // layer 2: h2 = tanh(h1 @ W2 + b2)  -- 32 independent accumulator chains
    float acc[HD];
#pragma unroll
    for (int j = 0; j < HD; ++j) acc[j] = b2[j];
#pragma unroll
    for (int i = 0; i < HD; ++i) {
        float hi = h1[i];
#pragma unroll
        for (int j = 0; j < HD; ++j)
            acc[j] = fmaf(hi, W2[i * HD + j], acc[j]);
    }
    // layer 3: softplus(h2 @ W3 + b3)
    float o = b3v;
#pragma unroll
    for (int j = 0; j < HD; ++j)
        o = fmaf(tanh_fast(acc[j]), W3[j], o);
    return softplus_fast(o);
}

__global__ __launch_bounds__(256) void gamma_rk4_kernel(
        const float4* __restrict__ inp, const float* __restrict__ gamma,
        const float* __restrict__ W1, const float* __restrict__ b1,
        const float* __restrict__ W2, const float* __restrict__ b2,
        const float* __restrict__ W3, const float* __restrict__ b3,
        float* __restrict__ out, int B)
{
    int idx = blockIdx.x * blockDim.x + threadIdx.x;
    if (idx >= B) return;

    float4 v = inp[idx];              // (B,4) row: eps_n, eps_half, eps_one, dt
    float eps_n = v.x, eps_h = v.y, eps_o = v.z, dt = v.w;
    float g   = gamma[idx];
    float b3v = b3[0];

    float k1 = dt * mlp_f(eps_n, g,  W1, b1, W2, b2, W3, b3v) * (eps_n - g);
    float g1 = fmaf(0.5f, k1, g);
    float k2 = dt * mlp_f(eps_h, g1, W1, b1, W2, b2, W3, b3v) * (eps_h - g1);
    float g2 = fmaf(0.5f, k2, g);
    float k3 = dt * mlp_f(eps_h, g2, W1, b1, W2, b2, W3, b3v) * (eps_h - g2);
    float g3 = g + k3;
    float k4 = dt * mlp_f(eps_o, g3, W1, b1, W2, b2, W3, b3v) * (eps_o - g3);

    out[idx] = g + (k1 + 2.0f * (k2 + k3) + k4) * (1.0f / 6.0f);
}

extern "C" void kernel_launch(void* const* d_in, const int* in_sizes, int n_in,
                              void* d_out, int out_size, void* d_ws, size_t ws_size,
                              hipStream_t stream) {
    const float4* inp   = (const float4*)d_in[0];  // (B,4) f32
    const float*  gamma = (const float*)d_in[1];   // (B,1) f32
    const float*  W1    = (const float*)d_in[2];   // (2,32)
    const float*  b1    = (const float*)d_in[3];   // (32,)
    const float*  W2    = (const float*)d_in[4];   // (32,32)
    const float*  b2    = (const float*)d_in[5];   // (32,)
    const float*  W3    = (const float*)d_in[6];   // (32,1)
    const float*  b3    = (const float*)d_in[7];   // (1,)
    float* out = (float*)d_out;

    int B = in_sizes[1];               // gamma element count == batch
    int block = 256;
    int grid = (B + block - 1) / block;
    gamma_rk4_kernel<<<grid, block, 0, stream>>>(inp, gamma, W1, b1, W2, b2,
                                                 W3, b3, out, B);
}

// Round 2
// 161.956 us; speedup vs baseline: 2.1493x; 2.1493x over previous
//
#include <hip/hip_runtime.h>

typedef __attribute__((ext_vector_type(8))) short bf16x8;
typedef __attribute__((ext_vector_type(16))) float f32x16;

__device__ __forceinline__ unsigned cvt_pk_bf16(float a, float b) {
    unsigned r;
    asm("v_cvt_pk_bf16_f32 %0, %1, %2" : "=v"(r) : "v"(a), "v"(b));
    return r;
}

__device__ __forceinline__ bf16x8 mk_frag(unsigned a, unsigned b, unsigned c, unsigned d) {
    union { unsigned u[4]; bf16x8 v; } x;
    x.u[0] = a; x.u[1] = b; x.u[2] = c; x.u[3] = d;
    return x.v;
}

__device__ __forceinline__ float tanh_fast(float x) {
    float t = __expf(2.0f * x);
    return 1.0f - __fdividef(2.0f, t + 1.0f);
}

__device__ __forceinline__ float mlp_f(float e, float g,
        const float* __restrict__ W1, const float* __restrict__ b1,
        bf16x8 Whi0, bf16x8 Whi1, bf16x8 Wlo0, bf16x8 Wlo1,
        const f32x16& b2v, const f32x16& w3v, float b3v)
{
    // layer 1 (fp32 VALU) + split-pack h1 into bf16 hi/lo pairs
    unsigned phi[16], plo[16];
#pragma unroll
    for (int m = 0; m < 16; ++m) {
        float a = tanh_fast(fmaf(e, W1[2*m],   fmaf(g, W1[32 + 2*m],   b1[2*m])));
        float b = tanh_fast(fmaf(e, W1[2*m+1], fmaf(g, W1[32 + 2*m+1], b1[2*m+1])));
        unsigned ph = cvt_pk_bf16(a, b);
        phi[m] = ph;
        float fa = __uint_as_float(ph << 16);
        float fb = __uint_as_float(ph & 0xffff0000u);
        plo[m] = cvt_pk_bf16(a - fa, b - fb);
    }
    // layer 2: pre2^T = W2^T @ h1^T  (two element-groups, two K-steps, 3-term split)
    f32x16 acc1 = b2v, acc2 = b2v;
#pragma unroll
    for (int s = 0; s < 2; ++s) {
        unsigned f1h[4], f2h[4], f1l[4], f2l[4];
#pragma unroll
        for (int j = 0; j < 4; ++j) {
            auto r = __builtin_amdgcn_permlane32_swap((int)phi[8*s + j], (int)phi[8*s + 4 + j], false, false);
            f1h[j] = (unsigned)r[0]; f2h[j] = (unsigned)r[1];
            auto q = __builtin_amdgcn_permlane32_swap((int)plo[8*s + j], (int)plo[8*s + 4 + j], false, false);
            f1l[j] = (unsigned)q[0]; f2l[j] = (unsigned)q[1];
        }
        bf16x8 B1h = mk_frag(f1h[0], f1h[1], f1h[2], f1h[3]);
        bf16x8 B2h = mk_frag(f2h[0], f2h[1], f2h[2], f2h[3]);
        bf16x8 B1l = mk_frag(f1l[0], f1l[1], f1l[2], f1l[3]);
        bf16x8 B2l = mk_frag(f2l[0], f2l[1], f2l[2], f2l[3]);
        bf16x8 Ah = s ? Whi1 : Whi0;
        bf16x8 Al = s ? Wlo1 : Wlo0;
        acc1 = __builtin_amdgcn_mfma_f32_32x32x16_bf16(Ah, B1h, acc1, 0, 0, 0);
        acc1 = __builtin_amdgcn_mfma_f32_32x32x16_bf16(Ah, B1l, acc1, 0, 0, 0);
        acc1 = __builtin_amdgcn_mfma_f32_32x32x16_bf16(Al, B1h, acc1, 0, 0, 0);
        acc2 = __builtin_amdgcn_mfma_f32_32x32x16_bf16(Ah, B2h, acc2, 0, 0, 0);
        acc2 = __builtin_amdgcn_mfma_f32_32x32x16_bf16(Ah, B2l, acc2, 0, 0, 0);
        acc2 = __builtin_amdgcn_mfma_f32_32x32x16_bf16(Al, B2h, acc2, 0, 0, 0);
    }
    // layer 3: per-lane partial dot over 16 rows, combine via one permlane swap
    float pA = 0.0f, pB = 0.0f;
#pragma unroll
    for (int r = 0; r < 16; ++r) {
        pA = fmaf(tanh_fast(acc1[r]), w3v[r], pA);
        pB = fmaf(tanh_fast(acc2[r]), w3v[r], pB);
    }
    auto c = __builtin_amdgcn_permlane32_swap(__float_as_int(pA), __float_as_int(pB), false, false);
    float o = __int_as_float(c[0]) + __int_as_float(c[1]) + b3v;
    return __logf(1.0f + __expf(o));   // softplus; |o| <~ 6, no overflow path
}

__global__ __launch_bounds__(256, 2) void gamma_rk4_mfma(
        const float4* __restrict__ inp, const float* __restrict__ gamma,
        const float* __restrict__ W1, const float* __restrict__ b1,
        const float* __restrict__ W2, const float* __restrict__ b2,
        const float* __restrict__ W3, const float* __restrict__ b3,
        float* __restrict__ out, int B)
{
    int idx  = blockIdx.x * 256 + threadIdx.x;
    int lane = threadIdx.x & 63;
    int hi   = lane >> 5;
    int arow = lane & 31;

    // A-operand: W2^T fragments (uniform), hi/lo bf16 split. lane l holds
    // A[row=l&31][k = 16*s + 8*(l>>5) + i], A[j][k] = W2[k][j].
    bf16x8 Whi[2], Wlo[2];
#pragma unroll
    for (int s = 0; s < 2; ++s) {
        unsigned wh[4], wl[4];
#pragma unroll
        for (int m = 0; m < 4; ++m) {
            float a = W2[(16*s + 8*hi + 2*m    ) * 32 + arow];
            float b = W2[(16*s + 8*hi + 2*m + 1) * 32 + arow];
            unsigned ph = cvt_pk_bf16(a, b);
            float fa = __uint_as_float(ph << 16);
            float fb = __uint_as_float(ph & 0xffff0000u);
            wh[m] = ph;
            wl[m] = cvt_pk_bf16(a - fa, b - fb);
        }
        Whi[s] = mk_frag(wh[0], wh[1], wh[2], wh[3]);
        Wlo[s] = mk_frag(wl[0], wl[1], wl[2], wl[3]);
    }
    // C/D row map: row = (r&3) + 8*(r>>2) + 4*hi  (col = element)
    f32x16 b2v, w3v;
#pragma unroll
    for (int r = 0; r < 16; ++r) {
        int row = (r & 3) + 8 * (r >> 2) + 4 * hi;
        b2v[r] = b2[row];
        w3v[r] = W3[row];
    }

    if (idx >= B) return;
    float4 v  = inp[idx];                 // eps_n, eps_half, eps_one, dt
    float g0  = gamma[idx];
    float b3v = b3[0];

    float k1 = v.w * mlp_f(v.x, g0, W1, b1, Whi[0], Whi[1], Wlo[0], Wlo[1], b2v, w3v, b3v) * (v.x - g0);
    float g1 = fmaf(0.5f, k1, g0);
    float k2 = v.w * mlp_f(v.y, g1, W1, b1, Whi[0], Whi[1], Wlo[0], Wlo[1], b2v, w3v, b3v) * (v.y - g1);
    float g2 = fmaf(0.5f, k2, g0);
    float k3 = v.w * mlp_f(v.y, g2, W1, b1, Whi[0], Whi[1], Wlo[0], Wlo[1], b2v, w3v, b3v) * (v.y - g2);
    float g3 = g0 + k3;
    float k4 = v.w * mlp_f(v.z, g3, W1, b1, Whi[0], Whi[1], Wlo[0], Wlo[1], b2v, w3v, b3v) * (v.z - g3);

    out[idx] = g0 + (k1 + 2.0f * (k2 + k3) + k4) * (1.0f / 6.0f);
}

extern "C" void kernel_launch(void* const* d_in, const int* in_sizes, int n_in,
                              void* d_out, int out_size, void* d_ws, size_t ws_size,
                              hipStream_t stream) {
    const float4* inp   = (const float4*)d_in[0];
    const float*  gamma = (const float*)d_in[1];
    const float*  W1    = (const float*)d_in[2];
    const float*  b1    = (const float*)d_in[3];
    const float*  W2    = (const float*)d_in[4];
    const float*  b2    = (const float*)d_in[5];
    const float*  W3    = (const float*)d_in[6];
    const float*  b3    = (const float*)d_in[7];
    float* out = (float*)d_out;

    int B = in_sizes[1];
    int block = 256;
    int grid = (B + block - 1) / block;
    gamma_rk4_mfma<<<grid, block, 0, stream>>>(inp, gamma, W1, b1, W2, b2,
                                               W3, b3, out, B);
}

// Round 3
// 66.001 us; speedup vs baseline: 5.2739x; 2.4538x over previous
//
#include <hip/hip_runtime.h>

typedef __attribute__((ext_vector_type(8))) short bf16x8;
typedef __attribute__((ext_vector_type(16))) float f32x16;

#define C2LE 2.8853900817779268f   // 2*log2(e)
#define NEG2C (-5.7707801635558537f) // -2*C2LE... (== -2c, folded into A')

__device__ __forceinline__ unsigned cvt_pk_bf16(float a, float b) {
    unsigned r;
    asm("v_cvt_pk_bf16_f32 %0, %1, %2" : "=v"(r) : "v"(a), "v"(b));
    return r;
}
__device__ __forceinline__ float exp2_fast(float x) {
    float r; asm("v_exp_f32 %0, %1" : "=v"(r) : "v"(x)); return r;
}
__device__ __forceinline__ float rcp_fast(float x) {
    float r; asm("v_rcp_f32 %0, %1" : "=v"(r) : "v"(x)); return r;
}
__device__ __forceinline__ bf16x8 mk_frag(unsigned a, unsigned b, unsigned c, unsigned d) {
    union { unsigned u[4]; bf16x8 v; } x;
    x.u[0] = a; x.u[1] = b; x.u[2] = c; x.u[3] = d;
    return x.v;
}

// r_j = 1/(exp2(c*pre_j)+1); tanh(pre_j) = 1 - 2*r_j  (folded into A'/w3m)
__device__ __forceinline__ float sigr(float pre) {
    return rcp_fast(exp2_fast(C2LE * pre) + 1.0f);
}

__device__ __forceinline__ float mlp_f(float e, float g,
        const float* __restrict__ W1, const float* __restrict__ b1,
        bf16x8 A0, bf16x8 A1, const f32x16& acc_base,
        const f32x16& w3m, float o0)
{
    // layer 1: r values (32), packed to bf16 pairs
    unsigned p[16];
#pragma unroll
    for (int m = 0; m < 16; ++m) {
        float ra = sigr(fmaf(e, W1[2*m],   fmaf(g, W1[32 + 2*m],   b1[2*m])));
        float rb = sigr(fmaf(e, W1[2*m+1], fmaf(g, W1[32 + 2*m+1], b1[2*m+1])));
        p[m] = cvt_pk_bf16(ra, rb);
    }
    // layer 2: acc = c*pre2^T = A' @ r + acc_base   (A' = -2c*W2^T)
    f32x16 acc1 = acc_base, acc2 = acc_base;
#pragma unroll
    for (int s = 0; s < 2; ++s) {
        unsigned f1[4], f2[4];
#pragma unroll
        for (int j = 0; j < 4; ++j) {
            auto r = __builtin_amdgcn_permlane32_swap((int)p[8*s + j], (int)p[8*s + 4 + j], false, false);
            f1[j] = (unsigned)r[0]; f2[j] = (unsigned)r[1];
        }
        bf16x8 B1 = mk_frag(f1[0], f1[1], f1[2], f1[3]);
        bf16x8 B2 = mk_frag(f2[0], f2[1], f2[2], f2[3]);
        bf16x8 A = s ? A1 : A0;
        acc1 = __builtin_amdgcn_mfma_f32_32x32x16_bf16(A, B1, acc1, 0, 0, 0);
        acc2 = __builtin_amdgcn_mfma_f32_32x32x16_bf16(A, B2, acc2, 0, 0, 0);
    }
    // layer 3: o = o0 + sum w3m[r] * r_row;  tanh folded (w3m = -2*W3, o0 = b3+sum W3)
    float pA = 0.0f, pB = 0.0f;
#pragma unroll
    for (int r = 0; r < 16; ++r) {
        float rA = rcp_fast(exp2_fast(acc1[r]) + 1.0f);
        float rB = rcp_fast(exp2_fast(acc2[r]) + 1.0f);
        pA = fmaf(w3m[r], rA, pA);
        pB = fmaf(w3m[r], rB, pB);
    }
    auto c = __builtin_amdgcn_permlane32_swap(__float_as_int(pA), __float_as_int(pB), false, false);
    float o = o0 + __int_as_float(c[0]) + __int_as_float(c[1]);
    return __logf(1.0f + __expf(o));   // softplus; |o| <~ 6
}

__global__ __launch_bounds__(256) void gamma_rk4_mfma(
        const float4* __restrict__ inp, const float* __restrict__ gamma,
        const float* __restrict__ W1, const float* __restrict__ b1,
        const float* __restrict__ W2, const float* __restrict__ b2,
        const float* __restrict__ W3, const float* __restrict__ b3,
        float* __restrict__ out, int B)
{
    int idx  = blockIdx.x * 256 + threadIdx.x;
    int lane = threadIdx.x & 63;
    int hi   = lane >> 5;
    int arow = lane & 31;

    // A' = -2c * W2^T in bf16.  lane l holds A'[row=l&31][k=16s+8*(l>>5)+i]
    bf16x8 A[2];
#pragma unroll
    for (int s = 0; s < 2; ++s) {
        unsigned w[4];
#pragma unroll
        for (int m = 0; m < 4; ++m) {
            float a = NEG2C * W2[(16*s + 8*hi + 2*m    ) * 32 + arow];
            float b = NEG2C * W2[(16*s + 8*hi + 2*m + 1) * 32 + arow];
            w[m] = cvt_pk_bf16(a, b);
        }
        A[s] = mk_frag(w[0], w[1], w[2], w[3]);
    }
    // C/D row map: row = (r&3) + 8*(r>>2) + 4*hi
    f32x16 cb2, w3m;
    float wsum = 0.0f;
#pragma unroll
    for (int r = 0; r < 16; ++r) {
        int row = (r & 3) + 8 * (r >> 2) + 4 * hi;
        cb2[r] = C2LE * b2[row];
        float w3 = W3[row];
        w3m[r] = -2.0f * w3;
        wsum  += w3;
    }
    // acc_base = c*b2 + c*colsum(W2) via MFMA with B = -0.5 (exact in bf16):
    // A' @ (-0.5) = (-2c*W2^T)(-0.5) = c*colsum
    {
        unsigned nh = 0xBF00BF00u;  // bf16(-0.5) pair
        bf16x8 negh = mk_frag(nh, nh, nh, nh);
        cb2 = __builtin_amdgcn_mfma_f32_32x32x16_bf16(A[0], negh, cb2, 0, 0, 0);
        cb2 = __builtin_amdgcn_mfma_f32_32x32x16_bf16(A[1], negh, cb2, 0, 0, 0);
    }
    // o0 = b3 + sum over ALL 32 rows of W3 (own 16 + partner 16 via swap)
    auto sw = __builtin_amdgcn_permlane32_swap(__float_as_int(wsum), __float_as_int(wsum), false, false);
    float o0 = b3[0] + __int_as_float(sw[0]) + __int_as_float(sw[1]);

    if (idx >= B) return;
    float4 v  = inp[idx];                 // eps_n, eps_half, eps_one, dt
    float g0  = gamma[idx];

    float k1 = v.w * mlp_f(v.x, g0, W1, b1, A[0], A[1], cb2, w3m, o0) * (v.x - g0);
    float g1 = fmaf(0.5f, k1, g0);
    float k2 = v.w * mlp_f(v.y, g1, W1, b1, A[0], A[1], cb2, w3m, o0) * (v.y - g1);
    float g2 = fmaf(0.5f, k2, g0);
    float k3 = v.w * mlp_f(v.y, g2, W1, b1, A[0], A[1], cb2, w3m, o0) * (v.y - g2);
    float g3 = g0 + k3;
    float k4 = v.w * mlp_f(v.z, g3, W1, b1, A[0], A[1], cb2, w3m, o0) * (v.z - g3);

    out[idx] = g0 + (k1 + 2.0f * (k2 + k3) + k4) * (1.0f / 6.0f);
}

extern "C" void kernel_launch(void* const* d_in, const int* in_sizes, int n_in,
                              void* d_out, int out_size, void* d_ws, size_t ws_size,
                              hipStream_t stream) {
    const float4* inp   = (const float4*)d_in[0];
    const float*  gamma = (const float*)d_in[1];
    const float*  W1    = (const float*)d_in[2];
    const float*  b1    = (const float*)d_in[3];
    const float*  W2    = (const float*)d_in[4];
    const float*  b2    = (const float*)d_in[5];
    const float*  W3    = (const float*)d_in[6];
    const float*  b3    = (const float*)d_in[7];
    float* out = (float*)d_out;

    int B = in_sizes[1];
    int block = 256;
    int grid = (B + block - 1) / block;
    gamma_rk4_mfma<<<grid, block, 0, stream>>>(inp, gamma, W1, b1, W2, b2,
                                               W3, b3, out, B);
}

// Round 5
// 62.949 us; speedup vs baseline: 5.5296x; 1.0485x over previous
//
#include <hip/hip_runtime.h>

typedef __attribute__((ext_vector_type(8))) short bf16x8;
typedef __attribute__((ext_vector_type(16))) float f32x16;

#define C2LE 2.8853900817779268f     // 2*log2(e)
#define NEG2C (-5.7707801635558537f) // -2*C2LE

static __device__ __forceinline__ unsigned cvt_pk_bf16(float a, float b) {
    unsigned r;
    asm("v_cvt_pk_bf16_f32 %0, %1, %2" : "=v"(r) : "v"(a), "v"(b));
    return r;
}
static __device__ __forceinline__ float exp2_r(float x) {
    float r; asm("v_exp_f32 %0, %1" : "=v"(r) : "v"(x)); return r;
}
static __device__ __forceinline__ float rcp_r(float x) {
    float r; asm("v_rcp_f32 %0, %1" : "=v"(r) : "v"(x)); return r;
}
static __device__ __forceinline__ bf16x8 mk_frag(unsigned a, unsigned b, unsigned c, unsigned d) {
    union { unsigned u[4]; bf16x8 v; } x;
    x.u[0]=a; x.u[1]=b; x.u[2]=c; x.u[3]=d; return x.v;
}

// f(e,g): L1 = MFMA (A = c*W1 hi/lo split, B = raw e,g hi/lo split),
// sigmoid r=1/(1+2^x) with pair-rcp, L2 = MFMA with A' = -2c*W2^T (tanh
// folded), L3 = VALU dot (tanh folded into w3m/o0).
static __device__ __forceinline__ float mlp_f(float e, float g,
        bf16x8 A1, const f32x16& cb1v,
        bf16x8 A20, bf16x8 A21, const f32x16& cb2v,
        const f32x16& w3m, float o0)
{
    // ---- layer 1 B-operand: k-slots [e_hi, e_lo, e_hi, g_hi, g_lo, g_hi, 0, 0]
    // (RAW e,g — the single c-scale lives in A1/cb1v)
    unsigned Ph = cvt_pk_bf16(e, g);
    float ehf = __uint_as_float(Ph << 16);
    float ghf = __uint_as_float(Ph & 0xffff0000u);
    unsigned Pl = cvt_pk_bf16(e - ehf, g - ghf);
    unsigned eh = Ph & 0xffffu, gh = Ph >> 16;
    unsigned el = Pl & 0xffffu, gl = Pl >> 16;
    unsigned w0 = eh | (el << 16);
    unsigned w1 = eh | (gh << 16);
    unsigned w2 = gl | (gh << 16);
    auto s0 = __builtin_amdgcn_permlane32_swap((int)w0, 0, false, false);
    auto s1 = __builtin_amdgcn_permlane32_swap((int)w1, 0, false, false);
    auto s2 = __builtin_amdgcn_permlane32_swap((int)w2, 0, false, false);
    bf16x8 Bg1 = mk_frag((unsigned)s0[0], (unsigned)s1[0], (unsigned)s2[0], 0u);
    bf16x8 Bg2 = mk_frag((unsigned)s0[1], (unsigned)s1[1], (unsigned)s2[1], 0u);
    f32x16 d1 = __builtin_amdgcn_mfma_f32_32x32x16_bf16(A1, Bg1, cb1v, 0, 0, 0);
    f32x16 d2 = __builtin_amdgcn_mfma_f32_32x32x16_bf16(A1, Bg2, cb1v, 0, 0, 0);

    // ---- sigmoid bank 1 (pair-rcp) + pack to bf16 pairs
    unsigned P[8], Q[8];
#pragma unroll
    for (int m = 0; m < 8; ++m) {
        float Ea = exp2_r(d1[2*m]), Eb = exp2_r(d1[2*m+1]);
        float da = Ea + 1.0f, db = Eb + 1.0f;
        float rd = rcp_r(da * db);
        P[m] = cvt_pk_bf16(rd * db, rd * da);
        float Ec = exp2_r(d2[2*m]), Ed = exp2_r(d2[2*m+1]);
        float dc = Ec + 1.0f, dd = Ed + 1.0f;
        float re = rcp_r(dc * dd);
        Q[m] = cvt_pk_bf16(re * dd, re * dc);
    }

    // ---- layer 2: acc = A' @ r + cb2v
    f32x16 a1 = cb2v, a2 = cb2v;
    {
        auto u02 = __builtin_amdgcn_permlane32_swap((int)P[0], (int)P[2], false, false);
        auto u13 = __builtin_amdgcn_permlane32_swap((int)P[1], (int)P[3], false, false);
        bf16x8 Bq = mk_frag((unsigned)u02[0], (unsigned)u13[0], (unsigned)u02[1], (unsigned)u13[1]);
        a1 = __builtin_amdgcn_mfma_f32_32x32x16_bf16(A20, Bq, a1, 0, 0, 0);
        auto v02 = __builtin_amdgcn_permlane32_swap((int)P[4], (int)P[6], false, false);
        auto v13 = __builtin_amdgcn_permlane32_swap((int)P[5], (int)P[7], false, false);
        bf16x8 Br = mk_frag((unsigned)v02[0], (unsigned)v13[0], (unsigned)v02[1], (unsigned)v13[1]);
        a1 = __builtin_amdgcn_mfma_f32_32x32x16_bf16(A21, Br, a1, 0, 0, 0);
    }
    {
        auto u02 = __builtin_amdgcn_permlane32_swap((int)Q[0], (int)Q[2], false, false);
        auto u13 = __builtin_amdgcn_permlane32_swap((int)Q[1], (int)Q[3], false, false);
        bf16x8 Bq = mk_frag((unsigned)u02[0], (unsigned)u13[0], (unsigned)u02[1], (unsigned)u13[1]);
        a2 = __builtin_amdgcn_mfma_f32_32x32x16_bf16(A20, Bq, a2, 0, 0, 0);
        auto v02 = __builtin_amdgcn_permlane32_swap((int)Q[4], (int)Q[6], false, false);
        auto v13 = __builtin_amdgcn_permlane32_swap((int)Q[5], (int)Q[7], false, false);
        bf16x8 Br = mk_frag((unsigned)v02[0], (unsigned)v13[0], (unsigned)v02[1], (unsigned)v13[1]);
        a2 = __builtin_amdgcn_mfma_f32_32x32x16_bf16(A21, Br, a2, 0, 0, 0);
    }

    // ---- layer 3: o = o0 + sum w3m[r]*sig(acc[r]) (pair-rcp)
    float pA = 0.0f, pB = 0.0f;
#pragma unroll
    for (int m = 0; m < 8; ++m) {
        float Ea = exp2_r(a1[2*m]), Eb = exp2_r(a1[2*m+1]);
        float da = Ea + 1.0f, db = Eb + 1.0f;
        float rd = rcp_r(da * db);
        pA = fmaf(w3m[2*m], rd * db, fmaf(w3m[2*m+1], rd * da, pA));
        float Ec = exp2_r(a2[2*m]), Ed = exp2_r(a2[2*m+1]);
        float dc = Ec + 1.0f, dd = Ed + 1.0f;
        float re = rcp_r(dc * dd);
        pB = fmaf(w3m[2*m], re * dd, fmaf(w3m[2*m+1], re * dc, pB));
    }
    auto c = __builtin_amdgcn_permlane32_swap(__float_as_int(pA), __float_as_int(pB), false, false);
    float o = o0 + __int_as_float(c[0]) + __int_as_float(c[1]);
    return __logf(1.0f + __expf(o));
}

__global__ __launch_bounds__(256, 1) void gamma_rk4_mfma(
        const float4* __restrict__ inp, const float* __restrict__ gamma,
        const float* __restrict__ W1, const float* __restrict__ b1,
        const float* __restrict__ W2, const float* __restrict__ b2,
        const float* __restrict__ W3, const float* __restrict__ b3,
        float* __restrict__ out, int B)
{
    int idx  = blockIdx.x * 256 + threadIdx.x;
    int lane = threadIdx.x & 63;
    int hi   = lane >> 5;
    int arow = lane & 31;

    // L1 A-frag: a = c*W1[0][j], b = c*W1[1][j], hi/lo split;
    // k-slots [a_hi, a_hi, a_lo, b_hi, b_hi, b_lo, 0, 0]; hi lanes zero.
    bf16x8 A1;
    {
        float ca = C2LE * W1[arow];
        float cb = C2LE * W1[32 + arow];
        unsigned Wh = cvt_pk_bf16(ca, cb);
        float ah = __uint_as_float(Wh << 16);
        float bh = __uint_as_float(Wh & 0xffff0000u);
        unsigned Wl = cvt_pk_bf16(ca - ah, cb - bh);
        unsigned ahi = Wh & 0xffffu, bhi = Wh >> 16;
        unsigned alo = Wl & 0xffffu, blo = Wl >> 16;
        A1 = hi ? mk_frag(0u, 0u, 0u, 0u)
                : mk_frag(ahi | (ahi << 16), alo | (bhi << 16), bhi | (blo << 16), 0u);
    }
    // L2 A' = -2c * W2^T in bf16 (two K=16 chunks)
    bf16x8 A2[2];
#pragma unroll
    for (int s = 0; s < 2; ++s) {
        unsigned w[4];
#pragma unroll
        for (int m = 0; m < 4; ++m) {
            float a = NEG2C * W2[(16*s + 8*hi + 2*m    ) * 32 + arow];
            float b = NEG2C * W2[(16*s + 8*hi + 2*m + 1) * 32 + arow];
            w[m] = cvt_pk_bf16(a, b);
        }
        A2[s] = mk_frag(w[0], w[1], w[2], w[3]);
    }
    // per-reg row map: row = (r&3) + 8*(r>>2) + 4*hi
    f32x16 cb1v, cb2v, w3m;
    float wsum = 0.0f;
#pragma unroll
    for (int r = 0; r < 16; ++r) {
        int row = (r & 3) + 8 * (r >> 2) + 4 * hi;
        cb1v[r] = C2LE * b1[row];
        cb2v[r] = C2LE * b2[row];
        float w3 = W3[row];
        w3m[r] = -2.0f * w3;
        wsum  += w3;
    }
    // cb2v += c*colsum(W2) via MFMA with B = -0.5 (exact in bf16)
    {
        unsigned nh = 0xBF00BF00u;
        bf16x8 negh = mk_frag(nh, nh, nh, nh);
        cb2v = __builtin_amdgcn_mfma_f32_32x32x16_bf16(A2[0], negh, cb2v, 0, 0, 0);
        cb2v = __builtin_amdgcn_mfma_f32_32x32x16_bf16(A2[1], negh, cb2v, 0, 0, 0);
    }
    auto sw = __builtin_amdgcn_permlane32_swap(__float_as_int(wsum), __float_as_int(wsum), false, false);
    float o0 = b3[0] + __int_as_float(sw[0]) + __int_as_float(sw[1]);

    if (idx >= B) return;
    float4 v  = inp[idx];                 // eps_n, eps_half, eps_one, dt
    float g0  = gamma[idx];

    float k1 = v.w * mlp_f(v.x, g0, A1, cb1v, A2[0], A2[1], cb2v, w3m, o0) * (v.x - g0);
    float g1 = fmaf(0.5f, k1, g0);
    float k2 = v.w * mlp_f(v.y, g1, A1, cb1v, A2[0], A2[1], cb2v, w3m, o0) * (v.y - g1);
    float g2 = fmaf(0.5f, k2, g0);
    float k3 = v.w * mlp_f(v.y, g2, A1, cb1v, A2[0], A2[1], cb2v, w3m, o0) * (v.y - g2);
    float g3 = g0 + k3;
    float k4 = v.w * mlp_f(v.z, g3, A1, cb1v, A2[0], A2[1], cb2v, w3m, o0) * (v.z - g3);

    out[idx] = g0 + (k1 + 2.0f * (k2 + k3) + k4) * (1.0f / 6.0f);
}

extern "C" void kernel_launch(void* const* d_in, const int* in_sizes, int n_in,
                              void* d_out, int out_size, void* d_ws, size_t ws_size,
                              hipStream_t stream) {
    const float4* inp   = (const float4*)d_in[0];
    const float*  gamma = (const float*)d_in[1];
    const float*  W1    = (const float*)d_in[2];
    const float*  b1    = (const float*)d_in[3];
    const float*  W2    = (const float*)d_in[4];
    const float*  b2    = (const float*)d_in[5];
    const float*  W3    = (const float*)d_in[6];
    const float*  b3    = (const float*)d_in[7];
    float* out = (float*)d_out;

    int B = in_sizes[1];
    int block = 256;
    int grid = (B + block - 1) / block;
    gamma_rk4_mfma<<<grid, block, 0, stream>>>(inp, gamma, W1, b1, W2, b2,
                                               W3, b3, out, B);
}